// Round 3
// baseline (266.488 us; speedup 1.0000x reference)
//
#include <hip/hip_runtime.h>
#include <hip/hip_fp16.h>

using i32x4  = __attribute__((ext_vector_type(4)))  int;
using i32x16 = __attribute__((ext_vector_type(16))) int;

static constexpr int M  = 4 * 2048;   // 8192 rows (B*S)
static constexpr int N  = 4096;       // OUT_F
static constexpr int K  = 4096;       // IN_F
static constexpr int BM = 256, BN = 256, BK = 64;
static constexpr int NT = K / BK;       // 64 K-tiles
static constexpr int TILE = BM * BK;    // 16384 bytes per packed int8 tile

// ---------------- pack kernels: int32 -> blocked int8 tiles in d_ws ----------
// tile layout (16 KB): [kg(4)][row(256)][16 bytes of k] -> off = kg*4096 + row*16
// wa: [M/256][NT][tile], wb: [N/256][NT][tile] (wb transposed: granule bytes walk k)

__device__ __forceinline__ unsigned pack4(i32x4 v) {
  return (unsigned)((v.x & 255) | ((v.y & 255) << 8) | ((v.z & 255) << 16) | (v.w << 24));
}

__global__ __launch_bounds__(256) void pack_x_kernel(const int* __restrict__ x,
                                                     unsigned char* __restrict__ wa) {
  unsigned g = blockIdx.x * 256 + threadIdx.x;   // dest 16B granule id, < M*K/16
  unsigned row = g & 255;
  unsigned kg  = (g >> 8) & 3;
  unsigned kt  = (g >> 10) & 63;
  unsigned br  = g >> 16;
  const int* src = x + ((size_t)(br * 256 + row) * K + kt * 64 + kg * 16);
  i32x4 v0 = *(const i32x4*)(src + 0);
  i32x4 v1 = *(const i32x4*)(src + 4);
  i32x4 v2 = *(const i32x4*)(src + 8);
  i32x4 v3 = *(const i32x4*)(src + 12);
  i32x4 d;
  d.x = (int)pack4(v0); d.y = (int)pack4(v1); d.z = (int)pack4(v2); d.w = (int)pack4(v3);
  *(i32x4*)(wa + (size_t)g * 16) = d;
}

__global__ __launch_bounds__(256) void pack_w_kernel(const int* __restrict__ w,
                                                     unsigned char* __restrict__ wb) {
  unsigned g = blockIdx.x * 256 + threadIdx.x;   // dest 16B granule id, < N*K/16
  unsigned col = g & 255;
  unsigned kg  = (g >> 8) & 3;
  unsigned kt  = (g >> 10) & 63;
  unsigned bn  = g >> 16;
  unsigned n   = bn * 256 + col;
  unsigned k0  = kt * 64 + kg * 16;
  const int* src = w + (size_t)k0 * N + n;
  i32x4 d;
#pragma unroll
  for (int j = 0; j < 4; ++j) {
    int b0 = src[(size_t)(j * 4 + 0) * N];
    int b1 = src[(size_t)(j * 4 + 1) * N];
    int b2 = src[(size_t)(j * 4 + 2) * N];
    int b3 = src[(size_t)(j * 4 + 3) * N];
    d[j] = (b0 & 255) | ((b1 & 255) << 8) | ((b2 & 255) << 16) | (b3 << 24);
  }
  *(i32x4*)(wb + (size_t)g * 16) = d;
}

// ------------- GEMM: 256x256, 4-phase interleave, triple-buffer, counted vmcnt

__device__ __forceinline__ void gload_lds16(const void* g, void* l) {
  __builtin_amdgcn_global_load_lds((const __attribute__((address_space(1))) unsigned int*)g,
                                   (__attribute__((address_space(3))) unsigned int*)l,
                                   16, 0, 0);
}

__global__ __launch_bounds__(512, 2) void gemm_i8(const unsigned char* __restrict__ wa,
                                                  const unsigned char* __restrict__ wb,
                                                  const __half* __restrict__ bias,
                                                  const float* __restrict__ alphaP,
                                                  float* __restrict__ out) {
  __shared__ __align__(16) unsigned char As[3][TILE];
  __shared__ __align__(16) unsigned char Bs[3][TILE];

  const int tid  = threadIdx.x;
  const int lane = tid & 63;
  const int w    = tid >> 6;            // wave 0..7
  const int wr   = w >> 2, wc = w & 3;  // 2 x 4 wave grid; wave tile 128x64
  const int l31  = lane & 31;
  const int kgl  = lane >> 5;

  // XCD-aware swizzle: nwg=512 (%8==0)
  const int bid = blockIdx.x;
  const int swz = (bid & 7) * 64 + (bid >> 3);
  const int bc  = swz & 15;             // N/256 = 16
  const int br  = swz >> 4;             // M/256 = 32

  const unsigned char* ga = wa + (size_t)br * NT * TILE;
  const unsigned char* gb = wb + (size_t)bc * NT * TILE;

  // stage quarter q of tile t into buf: q0/q1 = A halves, q2/q3 = B halves
  auto stage_q = [&](int buf, int t, int q) {
    const unsigned char* src = (q < 2 ? ga : gb) + (size_t)t * TILE + (q & 1) * 8192;
    unsigned char*       dst = (q < 2 ? As[buf] : Bs[buf]) + (q & 1) * 8192;
    gload_lds16(src + w * 1024 + lane * 16, dst + w * 1024);
  };

#pragma unroll
  for (int q = 0; q < 4; ++q) stage_q(0, 0, q);
#pragma unroll
  for (int q = 0; q < 4; ++q) stage_q(1, 1, q);

  i32x16 acc[4][2] = {};

  asm volatile("s_waitcnt vmcnt(4)" ::: "memory");   // tile 0 resident (tile 1 in flight)
  __builtin_amdgcn_s_barrier();

  const int arow = wr * 128 + l31;      // A frag row base (per lane)
  const int bcol = wc * 64 + l31;       // B frag col base (per lane)

  for (int t = 0; t < NT; ++t) {
    const unsigned char* Abase = As[t % 3] + kgl * 4096;   // kc chunk via +8192
    const unsigned char* Bbase = Bs[t % 3] + kgl * 4096;
    const bool pf   = (t + 2 < NT);
    const int  pbuf = (t + 2) % 3;

    i32x4 a0, a1, a2, a3, b0, b1;

    // ---- phase 0: read a[kc0][0,1], b[kc0][0,1]; mfma acc[0..1][0..1] (kc0)
    a0 = *(const i32x4*)(Abase + (arow +  0) * 16);
    a1 = *(const i32x4*)(Abase + (arow + 32) * 16);
    b0 = *(const i32x4*)(Bbase + (bcol +  0) * 16);
    b1 = *(const i32x4*)(Bbase + (bcol + 32) * 16);
    if (pf) stage_q(pbuf, t + 2, 0);
    __builtin_amdgcn_s_barrier();
    asm volatile("s_waitcnt lgkmcnt(0)" ::: "memory");
    __builtin_amdgcn_sched_barrier(0);
    __builtin_amdgcn_s_setprio(1);
    acc[0][0] = __builtin_amdgcn_mfma_i32_32x32x32_i8(a0, b0, acc[0][0], 0, 0, 0);
    acc[0][1] = __builtin_amdgcn_mfma_i32_32x32x32_i8(a0, b1, acc[0][1], 0, 0, 0);
    acc[1][0] = __builtin_amdgcn_mfma_i32_32x32x32_i8(a1, b0, acc[1][0], 0, 0, 0);
    acc[1][1] = __builtin_amdgcn_mfma_i32_32x32x32_i8(a1, b1, acc[1][1], 0, 0, 0);
    __builtin_amdgcn_s_setprio(0);
    __builtin_amdgcn_s_barrier();

    // ---- phase 1: read a[kc0][2,3]; mfma acc[2..3][0..1] (kc0)
    a2 = *(const i32x4*)(Abase + (arow + 64) * 16);
    a3 = *(const i32x4*)(Abase + (arow + 96) * 16);
    if (pf) stage_q(pbuf, t + 2, 1);
    __builtin_amdgcn_s_barrier();
    asm volatile("s_waitcnt lgkmcnt(0)" ::: "memory");
    __builtin_amdgcn_sched_barrier(0);
    __builtin_amdgcn_s_setprio(1);
    acc[2][0] = __builtin_amdgcn_mfma_i32_32x32x32_i8(a2, b0, acc[2][0], 0, 0, 0);
    acc[2][1] = __builtin_amdgcn_mfma_i32_32x32x32_i8(a2, b1, acc[2][1], 0, 0, 0);
    acc[3][0] = __builtin_amdgcn_mfma_i32_32x32x32_i8(a3, b0, acc[3][0], 0, 0, 0);
    acc[3][1] = __builtin_amdgcn_mfma_i32_32x32x32_i8(a3, b1, acc[3][1], 0, 0, 0);
    __builtin_amdgcn_s_setprio(0);
    __builtin_amdgcn_s_barrier();

    // ---- phase 2: read a[kc1][0,1], b[kc1][0,1]; mfma acc[0..1][0..1] (kc1)
    a0 = *(const i32x4*)(Abase + 8192 + (arow +  0) * 16);
    a1 = *(const i32x4*)(Abase + 8192 + (arow + 32) * 16);
    b0 = *(const i32x4*)(Bbase + 8192 + (bcol +  0) * 16);
    b1 = *(const i32x4*)(Bbase + 8192 + (bcol + 32) * 16);
    if (pf) stage_q(pbuf, t + 2, 2);
    __builtin_amdgcn_s_barrier();
    asm volatile("s_waitcnt lgkmcnt(0)" ::: "memory");
    __builtin_amdgcn_sched_barrier(0);
    __builtin_amdgcn_s_setprio(1);
    acc[0][0] = __builtin_amdgcn_mfma_i32_32x32x32_i8(a0, b0, acc[0][0], 0, 0, 0);
    acc[0][1] = __builtin_amdgcn_mfma_i32_32x32x32_i8(a0, b1, acc[0][1], 0, 0, 0);
    acc[1][0] = __builtin_amdgcn_mfma_i32_32x32x32_i8(a1, b0, acc[1][0], 0, 0, 0);
    acc[1][1] = __builtin_amdgcn_mfma_i32_32x32x32_i8(a1, b1, acc[1][1], 0, 0, 0);
    __builtin_amdgcn_s_setprio(0);
    __builtin_amdgcn_s_barrier();

    // ---- phase 3: read a[kc1][2,3]; mfma acc[2..3][0..1] (kc1); tail vmcnt
    a2 = *(const i32x4*)(Abase + 8192 + (arow + 64) * 16);
    a3 = *(const i32x4*)(Abase + 8192 + (arow + 96) * 16);
    if (pf) stage_q(pbuf, t + 2, 3);
    __builtin_amdgcn_s_barrier();
    asm volatile("s_waitcnt lgkmcnt(0)" ::: "memory");
    __builtin_amdgcn_sched_barrier(0);
    __builtin_amdgcn_s_setprio(1);
    acc[2][0] = __builtin_amdgcn_mfma_i32_32x32x32_i8(a2, b0, acc[2][0], 0, 0, 0);
    acc[2][1] = __builtin_amdgcn_mfma_i32_32x32x32_i8(a2, b1, acc[2][1], 0, 0, 0);
    acc[3][0] = __builtin_amdgcn_mfma_i32_32x32x32_i8(a3, b0, acc[3][0], 0, 0, 0);
    acc[3][1] = __builtin_amdgcn_mfma_i32_32x32x32_i8(a3, b1, acc[3][1], 0, 0, 0);
    __builtin_amdgcn_s_setprio(0);
    // make tile t+1 resident before its phase-0 reads; keep t+2's 4 loads in flight
    if (t + 2 < NT)      asm volatile("s_waitcnt vmcnt(4)" ::: "memory");
    else if (t + 1 < NT) asm volatile("s_waitcnt vmcnt(0)" ::: "memory");
    __builtin_amdgcn_s_barrier();
  }

  // epilogue: C/D layout col=lane&31, row=(r&3)+8*(r>>2)+4*(lane>>5)
  const float alpha = *alphaP;
  const int row0 = br * 256 + wr * 128 + 4 * kgl;
  const int col0 = bc * 256 + wc * 64 + l31;
#pragma unroll
  for (int ni = 0; ni < 2; ++ni) {
    const int col = col0 + ni * 32;
    const float bf = __half2float(bias[col]);
#pragma unroll
    for (int mi = 0; mi < 4; ++mi) {
#pragma unroll
      for (int r = 0; r < 16; ++r) {
        const int row = row0 + mi * 32 + (r & 3) + 8 * (r >> 2);
        out[(size_t)row * N + col] = ((float)acc[mi][ni][r] + bf) * alpha;
      }
    }
  }
}

extern "C" void kernel_launch(void* const* d_in, const int* in_sizes, int n_in,
                              void* d_out, int out_size, void* d_ws, size_t ws_size,
                              hipStream_t stream) {
  const int*    x     = (const int*)d_in[0];
  const int*    wgt   = (const int*)d_in[1];
  const __half* bias  = (const __half*)d_in[2];
  const float*  alpha = (const float*)d_in[3];
  float*        out   = (float*)d_out;

  // workspace: packed A (32 MB) + packed B (16 MB) = 48 MB
  unsigned char* wa = (unsigned char*)d_ws;
  unsigned char* wb = wa + (size_t)M * K;

  pack_x_kernel<<<(M * (size_t)K / 16) / 256, 256, 0, stream>>>(x, wa);
  pack_w_kernel<<<(N * (size_t)K / 16) / 256, 256, 0, stream>>>(wgt, wb);

  dim3 grid((M / BM) * (N / BN));   // 512 blocks
  gemm_i8<<<grid, 512, 0, stream>>>(wa, wb, bias, alpha, out);
}

// Round 4
// 240.447 us; speedup vs baseline: 1.1083x; 1.1083x over previous
//
#include <hip/hip_runtime.h>
#include <hip/hip_fp16.h>

using i32x4  = __attribute__((ext_vector_type(4)))  int;
using i32x16 = __attribute__((ext_vector_type(16))) int;

static constexpr int M  = 4 * 2048;   // 8192 rows (B*S)
static constexpr int N  = 4096;       // OUT_F
static constexpr int K  = 4096;       // IN_F
static constexpr int BM = 256, BN = 256, BK = 64;
static constexpr int NT = K / BK;       // 64 K-tiles
static constexpr int TILE = BM * BK;    // 16384 bytes per packed int8 tile

// ---------------- pack kernels: int32 -> blocked int8 tiles in d_ws ----------
// tile layout (16 KB): [kg(4)][row(256)][16 bytes of k] -> off = kg*4096 + row*16
// wa: [M/256][NT][tile], wb: [N/256][NT][tile] (wb transposed: granule bytes walk k)

__device__ __forceinline__ unsigned pack4(i32x4 v) {
  return (unsigned)((v.x & 255) | ((v.y & 255) << 8) | ((v.z & 255) << 16) | (v.w << 24));
}

__global__ __launch_bounds__(256) void pack_x_kernel(const int* __restrict__ x,
                                                     unsigned char* __restrict__ wa) {
  unsigned g = blockIdx.x * 256 + threadIdx.x;   // dest 16B granule id, < M*K/16
  unsigned row = g & 255;
  unsigned kg  = (g >> 8) & 3;
  unsigned kt  = (g >> 10) & 63;
  unsigned br  = g >> 16;
  const int* src = x + ((size_t)(br * 256 + row) * K + kt * 64 + kg * 16);
  i32x4 v0 = *(const i32x4*)(src + 0);
  i32x4 v1 = *(const i32x4*)(src + 4);
  i32x4 v2 = *(const i32x4*)(src + 8);
  i32x4 v3 = *(const i32x4*)(src + 12);
  i32x4 d;
  d.x = (int)pack4(v0); d.y = (int)pack4(v1); d.z = (int)pack4(v2); d.w = (int)pack4(v3);
  *(i32x4*)(wa + (size_t)g * 16) = d;
}

__global__ __launch_bounds__(256) void pack_w_kernel(const int* __restrict__ w,
                                                     unsigned char* __restrict__ wb) {
  unsigned g = blockIdx.x * 256 + threadIdx.x;   // dest 16B granule id, < N*K/16
  unsigned col = g & 255;
  unsigned kg  = (g >> 8) & 3;
  unsigned kt  = (g >> 10) & 63;
  unsigned bn  = g >> 16;
  unsigned n   = bn * 256 + col;
  unsigned k0  = kt * 64 + kg * 16;
  const int* src = w + (size_t)k0 * N + n;
  i32x4 d;
#pragma unroll
  for (int j = 0; j < 4; ++j) {
    int b0 = src[(size_t)(j * 4 + 0) * N];
    int b1 = src[(size_t)(j * 4 + 1) * N];
    int b2 = src[(size_t)(j * 4 + 2) * N];
    int b3 = src[(size_t)(j * 4 + 3) * N];
    d[j] = (b0 & 255) | ((b1 & 255) << 8) | ((b2 & 255) << 16) | (b3 << 24);
  }
  *(i32x4*)(wb + (size_t)g * 16) = d;
}

// ------- GEMM: 256x256, 2 phases per K-tile, triple-buffer, counted vmcnt ----

__device__ __forceinline__ void gload_lds16(const void* g, void* l) {
  __builtin_amdgcn_global_load_lds((const __attribute__((address_space(1))) unsigned int*)g,
                                   (__attribute__((address_space(3))) unsigned int*)l,
                                   16, 0, 0);
}

#define FENCE()   asm volatile("" ::: "memory")
#define BARRIER() do { FENCE(); __builtin_amdgcn_s_barrier(); FENCE(); } while (0)

__global__ __launch_bounds__(512, 2) void gemm_i8(const unsigned char* __restrict__ wa,
                                                  const unsigned char* __restrict__ wb,
                                                  const __half* __restrict__ bias,
                                                  const float* __restrict__ alphaP,
                                                  float* __restrict__ out) {
  __shared__ __align__(16) unsigned char As[3][TILE];
  __shared__ __align__(16) unsigned char Bs[3][TILE];

  const int tid  = threadIdx.x;
  const int lane = tid & 63;
  const int w    = tid >> 6;            // wave 0..7
  const int wr   = w >> 2, wc = w & 3;  // 2 x 4 wave grid; wave tile 128x64
  const int l31  = lane & 31;
  const int kgl  = lane >> 5;

  // XCD-aware swizzle: nwg=512 (%8==0)
  const int bid = blockIdx.x;
  const int swz = (bid & 7) * 64 + (bid >> 3);
  const int bc  = swz & 15;             // N/256 = 16
  const int br  = swz >> 4;             // M/256 = 32

  const unsigned char* ga = wa + (size_t)br * NT * TILE;
  const unsigned char* gb = wb + (size_t)bc * NT * TILE;

  // stage quarter q of tile t into buf: q0/q1 = A halves, q2/q3 = B halves
  auto stage_q = [&](int buf, int t, int q) {
    const unsigned char* src = (q < 2 ? ga : gb) + (size_t)t * TILE + (q & 1) * 8192;
    unsigned char*       dst = (q < 2 ? As[buf] : Bs[buf]) + (q & 1) * 8192;
    gload_lds16(src + w * 1024 + lane * 16, dst + w * 1024);
  };

#pragma unroll
  for (int q = 0; q < 4; ++q) stage_q(0, 0, q);
#pragma unroll
  for (int q = 0; q < 4; ++q) stage_q(1, 1, q);

  i32x16 acc[4][2] = {};

  asm volatile("s_waitcnt vmcnt(4)" ::: "memory");   // tile 0 resident (tile 1 in flight)
  BARRIER();

  const int arow = wr * 128 + l31;      // A frag row base (per lane)
  const int bcol = wc * 64 + l31;       // B frag col base (per lane)

  for (int t = 0; t < NT; ++t) {
    const unsigned char* Abase = As[t % 3] + kgl * 4096;   // kc1 chunk via +8192
    const unsigned char* Bbase = Bs[t % 3] + kgl * 4096;
    const bool pf   = (t + 2 < NT);
    const int  pbuf = (t + 2) % 3;

    i32x4 a0, a1, a2, a3, b0, b1;

    // ---- phase A: kc0 — 6 ds_read_b128 + 2 stage loads, barrier, 8 MFMA
    a0 = *(const i32x4*)(Abase + (arow +  0) * 16);
    a1 = *(const i32x4*)(Abase + (arow + 32) * 16);
    a2 = *(const i32x4*)(Abase + (arow + 64) * 16);
    a3 = *(const i32x4*)(Abase + (arow + 96) * 16);
    b0 = *(const i32x4*)(Bbase + (bcol +  0) * 16);
    b1 = *(const i32x4*)(Bbase + (bcol + 32) * 16);
    if (pf) { stage_q(pbuf, t + 2, 0); stage_q(pbuf, t + 2, 1); }
    BARRIER();
    // no explicit lgkmcnt: compiler emits per-operand lgkmcnt(N) -> wave stagger
    __builtin_amdgcn_s_setprio(1);
    acc[0][0] = __builtin_amdgcn_mfma_i32_32x32x32_i8(a0, b0, acc[0][0], 0, 0, 0);
    acc[0][1] = __builtin_amdgcn_mfma_i32_32x32x32_i8(a0, b1, acc[0][1], 0, 0, 0);
    acc[1][0] = __builtin_amdgcn_mfma_i32_32x32x32_i8(a1, b0, acc[1][0], 0, 0, 0);
    acc[1][1] = __builtin_amdgcn_mfma_i32_32x32x32_i8(a1, b1, acc[1][1], 0, 0, 0);
    acc[2][0] = __builtin_amdgcn_mfma_i32_32x32x32_i8(a2, b0, acc[2][0], 0, 0, 0);
    acc[2][1] = __builtin_amdgcn_mfma_i32_32x32x32_i8(a2, b1, acc[2][1], 0, 0, 0);
    acc[3][0] = __builtin_amdgcn_mfma_i32_32x32x32_i8(a3, b0, acc[3][0], 0, 0, 0);
    acc[3][1] = __builtin_amdgcn_mfma_i32_32x32x32_i8(a3, b1, acc[3][1], 0, 0, 0);
    __builtin_amdgcn_s_setprio(0);
    BARRIER();

    // ---- phase B: kc1 — 6 ds_read_b128 + 2 stage loads, vmcnt tail, 8 MFMA
    a0 = *(const i32x4*)(Abase + 8192 + (arow +  0) * 16);
    a1 = *(const i32x4*)(Abase + 8192 + (arow + 32) * 16);
    a2 = *(const i32x4*)(Abase + 8192 + (arow + 64) * 16);
    a3 = *(const i32x4*)(Abase + 8192 + (arow + 96) * 16);
    b0 = *(const i32x4*)(Bbase + 8192 + (bcol +  0) * 16);
    b1 = *(const i32x4*)(Bbase + 8192 + (bcol + 32) * 16);
    if (pf) { stage_q(pbuf, t + 2, 2); stage_q(pbuf, t + 2, 3); }
    // tile t+1 residency before next iteration's phase-A reads; never 0 mid-loop
    if (t + 2 < NT)      asm volatile("s_waitcnt vmcnt(4)" ::: "memory");
    else if (t + 1 < NT) asm volatile("s_waitcnt vmcnt(0)" ::: "memory");
    BARRIER();
    __builtin_amdgcn_s_setprio(1);
    acc[0][0] = __builtin_amdgcn_mfma_i32_32x32x32_i8(a0, b0, acc[0][0], 0, 0, 0);
    acc[0][1] = __builtin_amdgcn_mfma_i32_32x32x32_i8(a0, b1, acc[0][1], 0, 0, 0);
    acc[1][0] = __builtin_amdgcn_mfma_i32_32x32x32_i8(a1, b0, acc[1][0], 0, 0, 0);
    acc[1][1] = __builtin_amdgcn_mfma_i32_32x32x32_i8(a1, b1, acc[1][1], 0, 0, 0);
    acc[2][0] = __builtin_amdgcn_mfma_i32_32x32x32_i8(a2, b0, acc[2][0], 0, 0, 0);
    acc[2][1] = __builtin_amdgcn_mfma_i32_32x32x32_i8(a2, b1, acc[2][1], 0, 0, 0);
    acc[3][0] = __builtin_amdgcn_mfma_i32_32x32x32_i8(a3, b0, acc[3][0], 0, 0, 0);
    acc[3][1] = __builtin_amdgcn_mfma_i32_32x32x32_i8(a3, b1, acc[3][1], 0, 0, 0);
    __builtin_amdgcn_s_setprio(0);
    BARRIER();
  }

  // epilogue: C/D layout col=lane&31, row=(r&3)+8*(r>>2)+4*(lane>>5)
  const float alpha = *alphaP;
  const int row0 = br * 256 + wr * 128 + 4 * kgl;
  const int col0 = bc * 256 + wc * 64 + l31;
#pragma unroll
  for (int ni = 0; ni < 2; ++ni) {
    const int col = col0 + ni * 32;
    const float bf = __half2float(bias[col]);
#pragma unroll
    for (int mi = 0; mi < 4; ++mi) {
#pragma unroll
      for (int r = 0; r < 16; ++r) {
        const int row = row0 + mi * 32 + (r & 3) + 8 * (r >> 2);
        out[(size_t)row * N + col] = ((float)acc[mi][ni][r] + bf) * alpha;
      }
    }
  }
}

extern "C" void kernel_launch(void* const* d_in, const int* in_sizes, int n_in,
                              void* d_out, int out_size, void* d_ws, size_t ws_size,
                              hipStream_t stream) {
  const int*    x     = (const int*)d_in[0];
  const int*    wgt   = (const int*)d_in[1];
  const __half* bias  = (const __half*)d_in[2];
  const float*  alpha = (const float*)d_in[3];
  float*        out   = (float*)d_out;

  // workspace: packed A (32 MB) + packed B (16 MB) = 48 MB
  unsigned char* wa = (unsigned char*)d_ws;
  unsigned char* wb = wa + (size_t)M * K;

  pack_x_kernel<<<(M * (size_t)K / 16) / 256, 256, 0, stream>>>(x, wa);
  pack_w_kernel<<<(N * (size_t)K / 16) / 256, 256, 0, stream>>>(wgt, wb);

  dim3 grid((M / BM) * (N / BN));   // 512 blocks
  gemm_i8<<<grid, 512, 0, stream>>>(wa, wb, bias, alpha, out);
}